// Round 4
// baseline (359.032 us; speedup 1.0000x reference)
//
#include <hip/hip_runtime.h>

typedef _Float16 half8 __attribute__((ext_vector_type(8)));
typedef _Float16 half4 __attribute__((ext_vector_type(4)));
typedef float f32x4 __attribute__((ext_vector_type(4)));

#define BATCH 8
#define CH 128
#define NPIX 2304   // 48*48
#define LOG2E 1.44269504088896f

__device__ __forceinline__ f32x4 mfma32(half8 a, half8 b, f32x4 c) {
    return __builtin_amdgcn_mfma_f32_16x16x32_f16(a, b, c, 0, 0, 0);
}
__device__ __forceinline__ f32x4 mfma16(half4 a, half4 b, f32x4 c) {
    return __builtin_amdgcn_mfma_f32_16x16x16f16(a, b, c, 0, 0, 0);
}

// ---------------- fused prep: xpose (blocks 0..287), pool (288..1311), convW (1312..1503)
__global__ __launch_bounds__(256) void k_prep(
        const float* __restrict__ x, const float* __restrict__ Wq,
        const float* __restrict__ Wk, const float* __restrict__ Wv,
        _Float16* __restrict__ Wh, _Float16* __restrict__ xh, float* __restrict__ y0) {
    const int bid = blockIdx.x;
    const int t = threadIdx.x;
    __shared__ __align__(16) _Float16 xt[64 * 136];

    if (bid < 288) {                         // ---- x[b][c][n] f32 -> xh[b][n][c] f16
        const int n0 = (bid % 36) * 64, b = bid / 36;
        const float* xb = x + (size_t)b * CH * NPIX + n0;
        const int n = t & 63;
        const int c0b = (t >> 6) * 4;
        for (int rep = 0; rep < 8; ++rep) {
            int c0 = c0b + rep * 16;
            half4 h;
            h[0] = (_Float16)xb[(size_t)(c0 + 0) * NPIX + n];
            h[1] = (_Float16)xb[(size_t)(c0 + 1) * NPIX + n];
            h[2] = (_Float16)xb[(size_t)(c0 + 2) * NPIX + n];
            h[3] = (_Float16)xb[(size_t)(c0 + 3) * NPIX + n];
            *(half4*)(xt + n * 136 + c0) = h;
        }
        __syncthreads();
        _Float16* dst = xh + ((size_t)b * NPIX + n0) * CH;
        for (int rep = 0; rep < 4; ++rep) {
            int nn = rep * 16 + (t >> 4), c8 = (t & 15) * 8;
            *(half8*)(dst + nn * 128 + c8) = *(const half8*)(xt + nn * 136 + c8);
        }
    } else if (bid < 288 + 1024) {           // ---- global average pool
        const int row = bid - 288;            // b*128 + c
        const float4* p = (const float4*)(x + (size_t)row * NPIX);
        float s = 0.f;
        for (int tt = t; tt < NPIX / 4; tt += 256) {
            float4 v = p[tt];
            s += v.x + v.y + v.z + v.w;
        }
        for (int m = 1; m < 64; m <<= 1) s += __shfl_xor(s, m);
        __shared__ float ls[4];
        if ((t & 63) == 0) ls[t >> 6] = s;
        __syncthreads();
        if (t == 0) y0[row] = (ls[0] + ls[1] + ls[2] + ls[3]) * (1.0f / (float)NPIX);
    } else {                                  // ---- W f32 -> f16
        int i = (bid - 1312) * 256 + t;       // 0..49151
        const float* src = (i < 16384) ? Wq : ((i < 32768) ? Wk : Wv);
        Wh[i] = (_Float16)src[i & 16383];
    }
}

// ---------------- QKV projection (+SE on z==3) ----------------
// grid (18, 8, 4); block 256. z: 0=q (B,N,C), 1=k (B,N,C), 2=v (B,C,N), 3=SE (1 block)
__global__ __launch_bounds__(256) void k_proj(
        const _Float16* __restrict__ xh, const _Float16* __restrict__ Wh,
        const float* __restrict__ bq, const float* __restrict__ bk, const float* __restrict__ bv,
        _Float16* __restrict__ qT, _Float16* __restrict__ kT, _Float16* __restrict__ vN,
        const float* __restrict__ y0, const float* __restrict__ se_w1,
        const float* __restrict__ se_w2, float* __restrict__ scale) {
    const int which = blockIdx.z;
    const int t = threadIdx.x;

    if (which == 3) {                         // ---- SE MLP: 1 active block
        if (blockIdx.x != 0 || blockIdx.y != 0) return;
        __shared__ float ly[128];
        __shared__ float ly1[8];
        for (int b = 0; b < BATCH; ++b) {
            if (t < 128) ly[t] = y0[b * 128 + t];
            __syncthreads();
            if (t < 8) {
                float a = 0.f;
                for (int c = 0; c < 128; ++c) a += se_w1[t * 128 + c] * ly[c];
                ly1[t] = fmaxf(a, 0.f);
            }
            __syncthreads();
            if (t < 128) {
                float a = 0.f;
                for (int r = 0; r < 8; ++r) a += se_w2[t * 8 + r] * ly1[r];
                scale[b * 128 + t] = 1.f / (1.f + __expf(-a));
            }
            __syncthreads();
        }
        return;
    }

    const int n0 = blockIdx.x * 128;
    const int b = blockIdx.y;
    const float* bias = (which == 0) ? bq : ((which == 1) ? bk : bv);
    const _Float16* W = Wh + which * 16384;

    __shared__ __align__(16) _Float16 xt[128 * 128];  // swizzled tile

    { // stage xh tile [n][c], swizzled
        const _Float16* src = xh + ((size_t)b * NPIX + n0) * CH;
        for (int rep = 0; rep < 8; ++rep) {
            int row = rep * 16 + (t >> 4), ch = t & 15;
            *(half8*)(xt + row * 128 + ((ch ^ (row & 7)) * 8)) =
                *(const half8*)(src + row * 128 + ch * 8);
        }
    }
    __syncthreads();

    const int lane = t & 63, w = t >> 6;
    const int ln15 = lane & 15, quad = lane >> 4;

    f32x4 zero4 = {0.f, 0.f, 0.f, 0.f};
    f32x4 acc[8][2];
    for (int mt = 0; mt < 8; ++mt) { acc[mt][0] = zero4; acc[mt][1] = zero4; }

    for (int ks = 0; ks < 4; ++ks) {
        half8 bf[2];
        for (int nt = 0; nt < 2; ++nt) {
            int row = w * 32 + nt * 16 + ln15;
            int ch = ks * 4 + quad;
            bf[nt] = *(const half8*)(xt + row * 128 + ((ch ^ (row & 7)) * 8));
        }
        for (int mt = 0; mt < 8; ++mt) {
            half8 af = *(const half8*)(W + (mt * 16 + ln15) * 128 + ks * 32 + quad * 8);
            acc[mt][0] = mfma32(af, bf[0], acc[mt][0]);
            acc[mt][1] = mfma32(af, bf[1], acc[mt][1]);
        }
    }
    __syncthreads();   // xt reuse as transpose buffer

    if (which == 2) {
        // [c][n] swizzled, then coalesced store to vN (B,C,N)
        for (int mt = 0; mt < 8; ++mt)
            for (int nt = 0; nt < 2; ++nt)
                for (int r = 0; r < 4; ++r) {
                    int c = mt * 16 + quad * 4 + r;
                    int nl = w * 32 + nt * 16 + ln15;
                    xt[c * 128 + (((nl >> 3) ^ (c & 7)) * 8) + (nl & 7)] =
                        (_Float16)(acc[mt][nt][r] + bias[c]);
                }
        __syncthreads();
        _Float16* vb = vN + (size_t)b * CH * NPIX + n0;
        for (int rep = 0; rep < 8; ++rep) {
            int c = rep * 16 + (t >> 4), ch = t & 15;
            *(half8*)(vb + (size_t)c * NPIX + ch * 8) =
                *(const half8*)(xt + c * 128 + ((ch ^ (c & 7)) * 8));
        }
    } else {
        // [n][c] swizzled, then coalesced store to qT/kT (B,N,C)
        for (int mt = 0; mt < 8; ++mt)
            for (int nt = 0; nt < 2; ++nt)
                for (int r = 0; r < 4; ++r) {
                    int c = mt * 16 + quad * 4 + r;
                    int nl = w * 32 + nt * 16 + ln15;
                    xt[nl * 128 + (((c >> 3) ^ (nl & 7)) * 8) + (c & 7)] =
                        (_Float16)(acc[mt][nt][r] + bias[c]);
                }
        __syncthreads();
        _Float16* dst = ((which == 0) ? qT : kT) + ((size_t)b * NPIX + n0) * CH;
        for (int rep = 0; rep < 8; ++rep) {
            int nl = rep * 16 + (t >> 4), ch = t & 15;
            *(half8*)(dst + nl * 128 + ch * 8) =
                *(const half8*)(xt + nl * 128 + ((ch ^ (nl & 7)) * 8));
        }
    }
}

// ---------------- barrier-free flash attention, fused final epilogue ----------------
// grid (144, 8); block 256 (4 waves). Block: 16 q-rows; wave w takes j-tiles w,w+4,w+8,...
// S^T trick: D(row=j,col=i) -> softmax in-lane + 2 shuffles, P stays in registers
// as the exact B-frag of mfma_f32_16x16x16f16 for the PV product. No LDS in loop.
__global__ __launch_bounds__(256, 4) void k_attn(
        const _Float16* __restrict__ qT, const _Float16* __restrict__ kT,
        const _Float16* __restrict__ vN, const float* __restrict__ x,
        const float* __restrict__ scale, const float* __restrict__ gamma_p,
        float* __restrict__ out) {
    const int i0 = blockIdx.x * 16;
    const int b = blockIdx.y;
    const int t = threadIdx.x;
    const int lane = t & 63, w = t >> 6;
    const int ln15 = lane & 15, quad = lane >> 4;

    __shared__ float osb[4 * 128 * 16];   // [w][c][i] partial O^T
    __shared__ float lm[64], ll[64];      // [w][i]

    // Q frags: B-operand of S^T mfma. i = i0 + ln15 (same for all waves).
    half8 qf[4];
    {
        const _Float16* qb = qT + ((size_t)b * NPIX + i0 + ln15) * CH + quad * 8;
        for (int kc = 0; kc < 4; ++kc) qf[kc] = *(const half8*)(qb + kc * 32);
    }

    const _Float16* kp = kT + (size_t)b * NPIX * CH + (size_t)(w * 64 + ln15) * CH + quad * 8;
    const _Float16* vp = vN + (size_t)b * CH * NPIX + (size_t)ln15 * NPIX + w * 64 + quad * 4;

    f32x4 zero4 = {0.f, 0.f, 0.f, 0.f};
    f32x4 os[8];
    for (int ct = 0; ct < 8; ++ct) os[ct] = zero4;
    float m = -1e30f, l = 0.f;

    for (int it = 0; it < 9; ++it) {      // j0 = w*64 + it*256
        // ---- S^T = K·Q^T : D[j=quad*4+r (+16*jt)][i=ln15]
        f32x4 s[4];
        for (int jt = 0; jt < 4; ++jt) s[jt] = zero4;
        for (int jt = 0; jt < 4; ++jt) {
            const _Float16* kr = kp + jt * 16 * CH;
            for (int kc = 0; kc < 4; ++kc) {
                half8 kf = *(const half8*)(kr + kc * 32);
                s[jt] = mfma32(kf, qf[kc], s[jt]);
            }
        }

        // ---- online softmax: reduce over in-lane 16 values + 2 cross-quad shuffles
        float mx = fmaxf(fmaxf(s[0][0], s[0][1]), fmaxf(s[0][2], s[0][3]));
        for (int jt = 1; jt < 4; ++jt)
            mx = fmaxf(mx, fmaxf(fmaxf(s[jt][0], s[jt][1]), fmaxf(s[jt][2], s[jt][3])));
        mx = fmaxf(mx, __shfl_xor(mx, 16));
        mx = fmaxf(mx, __shfl_xor(mx, 32));
        float mnew = fmaxf(m, mx);
        float alpha = exp2f((m - mnew) * LOG2E);
        m = mnew;
        float mbias = mnew * LOG2E;

        float sum = 0.f;
        half4 pf[4];
        for (int jt = 0; jt < 4; ++jt)
            for (int r = 0; r < 4; ++r) {
                float p = exp2f(fmaf(s[jt][r], LOG2E, -mbias));
                sum += p;
                pf[jt][r] = (_Float16)p;
            }
        sum += __shfl_xor(sum, 16);
        sum += __shfl_xor(sum, 32);
        l = l * alpha + sum;

        for (int ct = 0; ct < 8; ++ct) {
            os[ct][0] *= alpha; os[ct][1] *= alpha;
            os[ct][2] *= alpha; os[ct][3] *= alpha;
        }

        // ---- O^T += V · P^T  (K=16 MFMA; P already in B-frag layout)
        const _Float16* vr = vp + it * 256;
        for (int ct = 0; ct < 8; ++ct) {
            const _Float16* vc = vr + (size_t)ct * 16 * NPIX;
            for (int jt = 0; jt < 4; ++jt) {
                half4 vf = *(const half4*)(vc + jt * 16);
                os[ct] = mfma16(vf, pf[jt], os[ct]);
            }
        }
        kp += 256 * CH;
    }

    // ---- merge 4 wave-partials + fused gamma/SE epilogue
    if (quad == 0) { lm[w * 16 + ln15] = m; ll[w * 16 + ln15] = l; }
    for (int ct = 0; ct < 8; ++ct)
        for (int r = 0; r < 4; ++r) {
            int c = ct * 16 + quad * 4 + r;
            osb[w * 2048 + c * 16 + ln15] = os[ct][r];
        }
    __syncthreads();

    {
        const int i = t & 15, c8 = (t >> 4) * 8;
        float m0 = lm[i], m1 = lm[16 + i], m2 = lm[32 + i], m3 = lm[48 + i];
        float M = fmaxf(fmaxf(m0, m1), fmaxf(m2, m3));
        float e0 = exp2f((m0 - M) * LOG2E), e1 = exp2f((m1 - M) * LOG2E);
        float e2 = exp2f((m2 - M) * LOG2E), e3 = exp2f((m3 - M) * LOG2E);
        float L = e0 * ll[i] + e1 * ll[16 + i] + e2 * ll[32 + i] + e3 * ll[48 + i];
        float inv = 1.f / L;
        float g = gamma_p[0];
        for (int cc = 0; cc < 8; ++cc) {
            int c = c8 + cc;
            float acc = e0 * osb[c * 16 + i] + e1 * osb[2048 + c * 16 + i] +
                        e2 * osb[4096 + c * 16 + i] + e3 * osb[6144 + c * 16 + i];
            size_t gi = (size_t)(b * 128 + c) * NPIX + i0 + i;
            out[gi] = g * (acc * inv) + x[gi] * scale[b * 128 + c];
        }
    }
}

// ---------------- host launcher ----------------
extern "C" void kernel_launch(void* const* d_in, const int* in_sizes, int n_in,
                              void* d_out, int out_size, void* d_ws, size_t ws_size,
                              hipStream_t stream) {
    const float* x     = (const float*)d_in[0];
    const float* Wq    = (const float*)d_in[1];
    const float* bq    = (const float*)d_in[2];
    const float* Wk    = (const float*)d_in[3];
    const float* bk    = (const float*)d_in[4];
    const float* Wv    = (const float*)d_in[5];
    const float* bv    = (const float*)d_in[6];
    const float* se_w1 = (const float*)d_in[7];
    const float* se_w2 = (const float*)d_in[8];
    const float* gamma = (const float*)d_in[9];
    float* out = (float*)d_out;

    char* ws = (char*)d_ws;
    const size_t E = (size_t)BATCH * NPIX * CH;          // 2,359,296 elems
    _Float16* qT = (_Float16*)(ws);                      // E f16
    _Float16* kT = (_Float16*)(ws + E * 2);
    _Float16* vN = (_Float16*)(ws + E * 4);
    _Float16* xh = (_Float16*)(ws + E * 6);
    _Float16* Wh = (_Float16*)(ws + E * 8);              // 49152 f16
    float* y0    = (float*)(ws + E * 8 + 98304);         // 1024 f32
    float* scale = (float*)(ws + E * 8 + 98304 + 4096);  // 1024 f32

    k_prep<<<1504, 256, 0, stream>>>(x, Wq, Wk, Wv, Wh, xh, y0);
    k_proj<<<dim3(NPIX / 128, BATCH, 4), 256, 0, stream>>>(
        xh, Wh, bq, bk, bv, qT, kT, vN, y0, se_w1, se_w2, scale);
    k_attn<<<dim3(NPIX / 16, BATCH), 256, 0, stream>>>(
        qT, kT, vN, x, scale, gamma, out);
}

// Round 5
// 165.002 us; speedup vs baseline: 2.1759x; 2.1759x over previous
//
#include <hip/hip_runtime.h>

typedef _Float16 half8 __attribute__((ext_vector_type(8)));
typedef _Float16 half4 __attribute__((ext_vector_type(4)));
typedef float f32x4 __attribute__((ext_vector_type(4)));

#define BATCH 8
#define CH 128
#define NPIX 2304   // 48*48
#define SPLIT 4
#define JPER (NPIX / SPLIT)          // 576 = 9 tiles of 64
#define BN (BATCH * NPIX)
#define LOG2E 1.44269504088896f

__device__ __forceinline__ f32x4 mfma32(half8 a, half8 b, f32x4 c) {
    return __builtin_amdgcn_mfma_f32_16x16x32_f16(a, b, c, 0, 0, 0);
}
__device__ __forceinline__ f32x4 mfma16(half4 a, half4 b, f32x4 c) {
    return __builtin_amdgcn_mfma_f32_16x16x16f16(a, b, c, 0, 0, 0);
}

// ---------------- prep: pool (blocks 0..1023), W convert (1024..1215) ----------------
__global__ __launch_bounds__(256) void k_prep(
        const float* __restrict__ x, const float* __restrict__ Wq,
        const float* __restrict__ Wk, const float* __restrict__ Wv,
        _Float16* __restrict__ Wh, float* __restrict__ y0) {
    const int bid = blockIdx.x;
    const int t = threadIdx.x;
    if (bid < 1024) {                        // ---- global average pool
        const int row = bid;                  // b*128 + c
        const float4* p = (const float4*)(x + (size_t)row * NPIX);
        float s = 0.f;
        for (int tt = t; tt < NPIX / 4; tt += 256) {
            float4 v = p[tt];
            s += v.x + v.y + v.z + v.w;
        }
        for (int m = 1; m < 64; m <<= 1) s += __shfl_xor(s, m);
        __shared__ float ls[4];
        if ((t & 63) == 0) ls[t >> 6] = s;
        __syncthreads();
        if (t == 0) y0[row] = (ls[0] + ls[1] + ls[2] + ls[3]) * (1.0f / (float)NPIX);
    } else {                                  // ---- W f32 -> f16
        int i = (bid - 1024) * 256 + t;       // 0..49151
        const float* src = (i < 16384) ? Wq : ((i < 32768) ? Wk : Wv);
        Wh[i] = (_Float16)src[i & 16383];
    }
}

// ---------------- QKV projection (x transposed in-LDS) + SE on z==3 ----------------
// grid (18, 8, 4); block 256. z: 0=q (B,N,C), 1=k (B,N,C), 2=v (B,C,N), 3=SE
__global__ __launch_bounds__(256) void k_proj(
        const float* __restrict__ x, const _Float16* __restrict__ Wh,
        const float* __restrict__ bq, const float* __restrict__ bk, const float* __restrict__ bv,
        _Float16* __restrict__ qT, _Float16* __restrict__ kT, _Float16* __restrict__ vN,
        const float* __restrict__ y0, const float* __restrict__ se_w1,
        const float* __restrict__ se_w2, float* __restrict__ scale) {
    const int which = blockIdx.z;
    const int t = threadIdx.x;

    if (which == 3) {                         // ---- SE MLP: 1 active block
        if (blockIdx.x != 0 || blockIdx.y != 0) return;
        __shared__ float ly[128];
        __shared__ float ly1[8];
        for (int b = 0; b < BATCH; ++b) {
            if (t < 128) ly[t] = y0[b * 128 + t];
            __syncthreads();
            if (t < 8) {
                float a = 0.f;
                for (int c = 0; c < 128; ++c) a += se_w1[t * 128 + c] * ly[c];
                ly1[t] = fmaxf(a, 0.f);
            }
            __syncthreads();
            if (t < 128) {
                float a = 0.f;
                for (int r = 0; r < 8; ++r) a += se_w2[t * 8 + r] * ly1[r];
                scale[b * 128 + t] = 1.f / (1.f + __expf(-a));
            }
            __syncthreads();
        }
        return;
    }

    const int n0 = blockIdx.x * 128;
    const int b = blockIdx.y;
    const float* bias = (which == 0) ? bq : ((which == 1) ? bk : bv);
    const _Float16* W = Wh + which * 16384;

    __shared__ __align__(16) _Float16 xt[128 * 128];  // swizzled [n][c]

    { // stage x tile: f32 (C-major) -> f16 transposed swizzled [n][c]
        const float* xb = x + (size_t)b * CH * NPIX + n0;
        for (int rep = 0; rep < 16; ++rep) {
            int flat = rep * 256 + t;
            int c = flat >> 5;                // 0..127
            int n4 = (flat & 31) * 4;         // 0..124
            float4 v4 = *(const float4*)(xb + (size_t)c * NPIX + n4);
            int cc = c & 7, ck = c >> 3;
            xt[(n4 + 0) * 128 + ((ck ^ ((n4 + 0) & 7)) * 8) + cc] = (_Float16)v4.x;
            xt[(n4 + 1) * 128 + ((ck ^ ((n4 + 1) & 7)) * 8) + cc] = (_Float16)v4.y;
            xt[(n4 + 2) * 128 + ((ck ^ ((n4 + 2) & 7)) * 8) + cc] = (_Float16)v4.z;
            xt[(n4 + 3) * 128 + ((ck ^ ((n4 + 3) & 7)) * 8) + cc] = (_Float16)v4.w;
        }
    }
    __syncthreads();

    const int lane = t & 63, w = t >> 6;
    const int ln15 = lane & 15, quad = lane >> 4;

    f32x4 zero4 = {0.f, 0.f, 0.f, 0.f};
    f32x4 acc[8][2];
    for (int mt = 0; mt < 8; ++mt) { acc[mt][0] = zero4; acc[mt][1] = zero4; }

    for (int ks = 0; ks < 4; ++ks) {
        half8 bf[2];
        for (int nt = 0; nt < 2; ++nt) {
            int row = w * 32 + nt * 16 + ln15;
            int ch = ks * 4 + quad;
            bf[nt] = *(const half8*)(xt + row * 128 + ((ch ^ (row & 7)) * 8));
        }
        for (int mt = 0; mt < 8; ++mt) {
            half8 af = *(const half8*)(W + (mt * 16 + ln15) * 128 + ks * 32 + quad * 8);
            acc[mt][0] = mfma32(af, bf[0], acc[mt][0]);
            acc[mt][1] = mfma32(af, bf[1], acc[mt][1]);
        }
    }
    __syncthreads();   // xt reuse as transpose buffer

    if (which == 2) {
        // [c][n] swizzled, then coalesced store to vN (B,C,N)
        for (int mt = 0; mt < 8; ++mt)
            for (int nt = 0; nt < 2; ++nt)
                for (int r = 0; r < 4; ++r) {
                    int c = mt * 16 + quad * 4 + r;
                    int nl = w * 32 + nt * 16 + ln15;
                    xt[c * 128 + (((nl >> 3) ^ (c & 7)) * 8) + (nl & 7)] =
                        (_Float16)(acc[mt][nt][r] + bias[c]);
                }
        __syncthreads();
        _Float16* vb = vN + (size_t)b * CH * NPIX + n0;
        for (int rep = 0; rep < 8; ++rep) {
            int c = rep * 16 + (t >> 4), ch = t & 15;
            *(half8*)(vb + (size_t)c * NPIX + ch * 8) =
                *(const half8*)(xt + c * 128 + ((ch ^ (c & 7)) * 8));
        }
    } else {
        // [n][c] swizzled, then coalesced store to qT/kT (B,N,C)
        for (int mt = 0; mt < 8; ++mt)
            for (int nt = 0; nt < 2; ++nt)
                for (int r = 0; r < 4; ++r) {
                    int c = mt * 16 + quad * 4 + r;
                    int nl = w * 32 + nt * 16 + ln15;
                    xt[nl * 128 + (((c >> 3) ^ (nl & 7)) * 8) + (c & 7)] =
                        (_Float16)(acc[mt][nt][r] + bias[c]);
                }
        __syncthreads();
        _Float16* dst = ((which == 0) ? qT : kT) + ((size_t)b * NPIX + n0) * CH;
        for (int rep = 0; rep < 8; ++rep) {
            int nl = rep * 16 + (t >> 4), ch = t & 15;
            *(half8*)(dst + nl * 128 + ch * 8) =
                *(const half8*)(xt + nl * 128 + ((ch ^ (nl & 7)) * 8));
        }
    }
}

// ---------------- flash attention: LDS K/V shared by 4 i-strips, S^T softmax ----------------
// grid (36, 8, SPLIT); block 256. Wave w owns i-rows i0+16w..+15; all waves share K/V tile.
__global__ __launch_bounds__(256, 4) void k_attn(
        const _Float16* __restrict__ qT, const _Float16* __restrict__ kT,
        const _Float16* __restrict__ vN,
        _Float16* __restrict__ o_part, float* __restrict__ g_m, float* __restrict__ g_l) {
    const int i0 = blockIdx.x * 64;
    const int b = blockIdx.y;
    const int split = blockIdx.z;
    const int t = threadIdx.x;
    const int lane = t & 63, w = t >> 6;
    const int ln15 = lane & 15, quad = lane >> 4;

    __shared__ __align__(16) _Float16 sh[16384];   // k_s = sh (64x128), v_s = sh+8192 (128x64)
    _Float16* k_s = sh;
    _Float16* v_s = sh + 8192;

    // Q frags (B-operand of S^T): i = i0 + 16w + ln15
    half8 qf[4];
    {
        const _Float16* qb = qT + ((size_t)b * NPIX + i0 + w * 16 + ln15) * CH + quad * 8;
        for (int kc = 0; kc < 4; ++kc) qf[kc] = *(const half8*)(qb + kc * 32);
    }

    f32x4 zero4 = {0.f, 0.f, 0.f, 0.f};
    f32x4 os[8];
    for (int ct = 0; ct < 8; ++ct) os[ct] = zero4;
    float m = -1e30f, l = 0.f;

    for (int it = 0; it < 9; ++it) {
        const int j0 = split * JPER + it * 64;
        __syncthreads();   // prior consumers of k_s/v_s done
        { // stage K tile [j][c] swizzled (16KB)
            const _Float16* kb = kT + ((size_t)b * NPIX + j0) * CH;
            for (int rep = 0; rep < 4; ++rep) {
                int row = rep * 16 + (t >> 4), ch = t & 15;
                *(half8*)(k_s + row * 128 + ((ch ^ (row & 7)) * 8)) =
                    *(const half8*)(kb + row * CH + ch * 8);
            }
        }
        { // stage V tile [c][j] swizzled (16KB)
            const _Float16* vb = vN + (size_t)b * CH * NPIX + j0;
            for (int rep = 0; rep < 4; ++rep) {
                int c = rep * 32 + (t >> 3), ch = t & 7;
                *(half8*)(v_s + c * 64 + ((ch ^ (c & 7)) * 8)) =
                    *(const half8*)(vb + (size_t)c * NPIX + ch * 8);
            }
        }
        __syncthreads();

        // ---- S^T = K·Q^T : D[j = 16jt + quad*4+r][i = ln15]
        f32x4 s[4];
        for (int jt = 0; jt < 4; ++jt) s[jt] = zero4;
        for (int jt = 0; jt < 4; ++jt) {
            for (int kc = 0; kc < 4; ++kc) {
                int row = jt * 16 + ln15, ch = kc * 4 + quad;
                half8 kf = *(const half8*)(k_s + row * 128 + ((ch ^ (row & 7)) * 8));
                s[jt] = mfma32(kf, qf[kc], s[jt]);
            }
        }

        // ---- online softmax: 16 in-lane values + 2 cross-quad shuffles
        float mx = fmaxf(fmaxf(s[0][0], s[0][1]), fmaxf(s[0][2], s[0][3]));
        for (int jt = 1; jt < 4; ++jt)
            mx = fmaxf(mx, fmaxf(fmaxf(s[jt][0], s[jt][1]), fmaxf(s[jt][2], s[jt][3])));
        mx = fmaxf(mx, __shfl_xor(mx, 16));
        mx = fmaxf(mx, __shfl_xor(mx, 32));
        float mnew = fmaxf(m, mx);
        float alpha = exp2f((m - mnew) * LOG2E);
        m = mnew;
        float mbias = mnew * LOG2E;

        float sum = 0.f;
        half4 pf[4];
        for (int jt = 0; jt < 4; ++jt)
            for (int r = 0; r < 4; ++r) {
                float p = exp2f(fmaf(s[jt][r], LOG2E, -mbias));
                sum += p;
                pf[jt][r] = (_Float16)p;
            }
        sum += __shfl_xor(sum, 16);
        sum += __shfl_xor(sum, 32);
        l = l * alpha + sum;

        for (int ct = 0; ct < 8; ++ct) {
            os[ct][0] *= alpha; os[ct][1] *= alpha;
            os[ct][2] *= alpha; os[ct][3] *= alpha;
        }

        // ---- O^T += V · P^T  (K=16 MFMA; P in registers, V from LDS)
        for (int ct = 0; ct < 8; ++ct) {
            int c = ct * 16 + ln15;
            for (int jt = 0; jt < 4; ++jt) {
                int chunk = jt * 2 + (quad >> 1);
                half4 vf = *(const half4*)(v_s + c * 64 + ((chunk ^ (c & 7)) * 8) + (quad & 1) * 4);
                os[ct] = mfma16(vf, pf[jt], os[ct]);
            }
        }
    }

    // ---- epilogue: m/l out; O^T f16 via LDS transpose, coalesced store
    if (quad == 0) {
        int i = i0 + w * 16 + ln15;
        g_m[(size_t)(split * BATCH + b) * NPIX + i] = m;
        g_l[(size_t)(split * BATCH + b) * NPIX + i] = l;
    }
    __syncthreads();   // all LDS reads done before reuse
    for (int ct = 0; ct < 8; ++ct)
        for (int r = 0; r < 4; ++r) {
            int c = ct * 16 + quad * 4 + r;
            int il = w * 16 + ln15;
            int chunk = (il >> 3);
            sh[c * 64 + ((chunk ^ (c & 7)) * 8) + (il & 7)] = (_Float16)os[ct][r];
        }
    __syncthreads();
    _Float16* op = o_part + (size_t)(split * BATCH + b) * CH * NPIX;
    for (int rep = 0; rep < 4; ++rep) {
        int c = rep * 32 + (t >> 3), ch = t & 7;
        *(half8*)(op + (size_t)c * NPIX + i0 + ch * 8) =
            *(const half8*)(sh + c * 64 + ((ch ^ (c & 7)) * 8));
    }
}

// ---------------- combine (fused split-weights) + SE epilogue ----------------
// grid (36, 8); block 256
__global__ __launch_bounds__(256) void k_combine(
        const _Float16* __restrict__ o_part, const float* __restrict__ g_m,
        const float* __restrict__ g_l, const float* __restrict__ x,
        const float* __restrict__ scale, const float* __restrict__ gamma_p,
        float* __restrict__ out) {
    const int i0 = blockIdx.x * 64;
    const int b = blockIdx.y;
    const int t = threadIdx.x;
    __shared__ float wl[SPLIT][64];

    if (t < 64) {
        int i = i0 + t;
        float mm[SPLIT], llv[SPLIT];
        float M = -1e30f;
        for (int s = 0; s < SPLIT; ++s) {
            mm[s] = g_m[(size_t)(s * BATCH + b) * NPIX + i];
            llv[s] = g_l[(size_t)(s * BATCH + b) * NPIX + i];
            M = fmaxf(M, mm[s]);
        }
        float L = 0.f, e[SPLIT];
        for (int s = 0; s < SPLIT; ++s) {
            e[s] = exp2f((mm[s] - M) * LOG2E);
            L += e[s] * llv[s];
        }
        float inv = 1.f / L;
        for (int s = 0; s < SPLIT; ++s) wl[s][t] = e[s] * inv;
    }
    __syncthreads();

    const float g = gamma_p[0];
    for (int rep = 0; rep < 4; ++rep) {
        int c = rep * 32 + (t >> 3), i8 = (t & 7) * 8;
        size_t base = ((size_t)b * CH + c) * NPIX + i0 + i8;
        float acc[8] = {0.f, 0.f, 0.f, 0.f, 0.f, 0.f, 0.f, 0.f};
        for (int s = 0; s < SPLIT; ++s) {
            half8 o = *(const half8*)(o_part +
                ((size_t)(s * BATCH + b) * CH + c) * NPIX + i0 + i8);
            for (int e = 0; e < 8; ++e) acc[e] += wl[s][i8 + e] * (float)o[e];
        }
        float sc = scale[b * 128 + c];
        float4 x0 = *(const float4*)(x + base);
        float4 x1 = *(const float4*)(x + base + 4);
        float4 r0, r1;
        r0.x = g * acc[0] + x0.x * sc; r0.y = g * acc[1] + x0.y * sc;
        r0.z = g * acc[2] + x0.z * sc; r0.w = g * acc[3] + x0.w * sc;
        r1.x = g * acc[4] + x1.x * sc; r1.y = g * acc[5] + x1.y * sc;
        r1.z = g * acc[6] + x1.z * sc; r1.w = g * acc[7] + x1.w * sc;
        *(float4*)(out + base) = r0;
        *(float4*)(out + base + 4) = r1;
    }
}

// ---------------- host launcher ----------------
extern "C" void kernel_launch(void* const* d_in, const int* in_sizes, int n_in,
                              void* d_out, int out_size, void* d_ws, size_t ws_size,
                              hipStream_t stream) {
    const float* x     = (const float*)d_in[0];
    const float* Wq    = (const float*)d_in[1];
    const float* bq    = (const float*)d_in[2];
    const float* Wk    = (const float*)d_in[3];
    const float* bk    = (const float*)d_in[4];
    const float* Wv    = (const float*)d_in[5];
    const float* bv    = (const float*)d_in[6];
    const float* se_w1 = (const float*)d_in[7];
    const float* se_w2 = (const float*)d_in[8];
    const float* gamma = (const float*)d_in[9];
    float* out = (float*)d_out;

    char* ws = (char*)d_ws;
    const size_t E = (size_t)BATCH * NPIX * CH;          // 2,359,296 elems
    _Float16* qT = (_Float16*)(ws);                      // E f16
    _Float16* kT = (_Float16*)(ws + E * 2);
    _Float16* vN = (_Float16*)(ws + E * 4);
    _Float16* op = (_Float16*)(ws + E * 6);              // SPLIT*E f16
    char* tail   = ws + E * 6 + (size_t)SPLIT * E * 2;
    _Float16* Wh = (_Float16*)(tail);                    // 49152 f16
    float* g_m   = (float*)(tail + 98304);
    float* g_l   = (float*)(tail + 98304 + SPLIT * BN * 4);
    float* y0    = (float*)(tail + 98304 + 2 * SPLIT * BN * 4);
    float* scale = (float*)(tail + 98304 + 2 * SPLIT * BN * 4 + 4096);

    k_prep<<<1216, 256, 0, stream>>>(x, Wq, Wk, Wv, Wh, y0);
    k_proj<<<dim3(NPIX / 128, BATCH, 4), 256, 0, stream>>>(
        x, Wh, bq, bk, bv, qT, kT, vN, y0, se_w1, se_w2, scale);
    k_attn<<<dim3(NPIX / 64, BATCH, SPLIT), 256, 0, stream>>>(
        qT, kT, vN, op, g_m, g_l);
    k_combine<<<dim3(NPIX / 64, BATCH), 256, 0, stream>>>(
        op, g_m, g_l, x, scale, gamma, out);
}